// Round 1
// baseline (3171.497 us; speedup 1.0000x reference)
//
#include <hip/hip_runtime.h>
#include <hip/hip_bf16.h>
#include <cstdint>
#include <cstddef>

#define DIM 4096
#define HIDDEN 11008
#define MTOK 8192   // B*S = 4*2048

typedef __bf16 bf16x8 __attribute__((ext_vector_type(8)));
typedef float floatx4 __attribute__((ext_vector_type(4)));

__device__ __forceinline__ unsigned short f2bf(float f) {
    union { float f; unsigned int u; } v; v.f = f;
    unsigned int r = v.u + 0x7FFFu + ((v.u >> 16) & 1u);
    return (unsigned short)(r >> 16);
}

__device__ __forceinline__ void gload16(const void* g, void* l) {
    __builtin_amdgcn_global_load_lds(
        (const __attribute__((address_space(1))) unsigned int*)g,
        (__attribute__((address_space(3))) unsigned int*)l,
        16, 0, 0);
}

__device__ __forceinline__ floatx4 mfma16(bf16x8 a, bf16x8 b, floatx4 c) {
    return __builtin_amdgcn_mfma_f32_16x16x32_bf16(a, b, c, 0, 0, 0);
}

// ---------------- conversion kernels ----------------

__global__ void cvt_f32_bf16(const float4* __restrict__ in, ushort4* __restrict__ out, int n4) {
    int i = blockIdx.x * 256 + threadIdx.x;
    if (i < n4) {
        float4 v = in[i];
        ushort4 o;
        o.x = f2bf(v.x); o.y = f2bf(v.y); o.z = f2bf(v.z); o.w = f2bf(v.w);
        out[i] = o;
    }
}

__global__ void cvt_i32_bf16(const int4* __restrict__ in, ushort4* __restrict__ out, int n4) {
    int i = blockIdx.x * 256 + threadIdx.x;
    if (i < n4) {
        int4 v = in[i];
        ushort4 o;
        o.x = f2bf((float)v.x); o.y = f2bf((float)v.y);
        o.z = f2bf((float)v.z); o.w = f2bf((float)v.w);
        out[i] = o;
    }
}

// ---------------- GEMM1: fused gate+up+SwiGLU ----------------
// A [MTOK,DIM] bf16 row-major; Bg,Bu [HIDDEN,DIM] bf16 row-major (NT).
// Block tile: 128 rows x 64 cols, computing BOTH gate and up; writes
// mid[m,n] = silu(g*sg) * (u*su) as bf16.
__global__ __launch_bounds__(256) void gemm_gateup(
    const unsigned short* __restrict__ A,
    const unsigned short* __restrict__ Bg,
    const unsigned short* __restrict__ Bu,
    unsigned short* __restrict__ mid,
    const float* __restrict__ sgp, const float* __restrict__ sup)
{
    __shared__ __align__(16) unsigned short sA[128 * 32];
    __shared__ __align__(16) unsigned short sBg[64 * 32];
    __shared__ __align__(16) unsigned short sBu[64 * 32];

    const int tid  = threadIdx.x;
    const int lane = tid & 63;
    const int wave = tid >> 6;
    const int wr   = wave >> 1;     // 0..1 : which 64-row half
    const int wc   = wave & 1;      // 0..1 : which 32-col half
    const int quad = lane >> 4;     // 0..3
    const int l16  = lane & 15;

    const size_t m0 = (size_t)blockIdx.x * 128;
    const size_t n0 = (size_t)blockIdx.y * 64;

    // staging: each thread loads 16B; row = tid>>2, col8 = (tid&3)*8
    const int srow = tid >> 2;
    const int scol = (tid & 3) * 8;

    const unsigned short* gA0 = A  + (m0 + srow) * DIM + scol;
    const unsigned short* gA1 = gA0 + (size_t)64 * DIM;
    const unsigned short* gBg = Bg + (n0 + srow) * DIM + scol;
    const unsigned short* gBu = Bu + (n0 + srow) * DIM + scol;

    unsigned short* lA0 = &sA[tid * 8];
    unsigned short* lA1 = &sA[(tid + 256) * 8];
    unsigned short* lBg = &sBg[tid * 8];
    unsigned short* lBu = &sBu[tid * 8];

    // fragment read pointers (A-operand layout: m=lane&15, k=quad*8..+7)
    const unsigned short* rA[4];
    const unsigned short* rBg[2];
    const unsigned short* rBu[2];
    for (int i = 0; i < 4; ++i)
        rA[i] = &sA[(wr * 64 + i * 16 + l16) * 32 + quad * 8];
    for (int j = 0; j < 2; ++j) {
        rBg[j] = &sBg[(wc * 32 + j * 16 + l16) * 32 + quad * 8];
        rBu[j] = &sBu[(wc * 32 + j * 16 + l16) * 32 + quad * 8];
    }

    floatx4 accg[4][2], accu[4][2];
    const floatx4 zero = {0.f, 0.f, 0.f, 0.f};
    for (int i = 0; i < 4; ++i)
        for (int j = 0; j < 2; ++j) { accg[i][j] = zero; accu[i][j] = zero; }

    for (int kt = 0; kt < DIM / 32; ++kt) {
        __syncthreads();   // prior compute done before we overwrite LDS
        gload16(gA0, lA0);
        gload16(gA1, lA1);
        gload16(gBg, lBg);
        gload16(gBu, lBu);
        gA0 += 32; gA1 += 32; gBg += 32; gBu += 32;
        __syncthreads();   // drains vmcnt: LDS writes visible

        bf16x8 af[4], bg[2], bu[2];
        for (int i = 0; i < 4; ++i) af[i] = *(const bf16x8*)rA[i];
        for (int j = 0; j < 2; ++j) {
            bg[j] = *(const bf16x8*)rBg[j];
            bu[j] = *(const bf16x8*)rBu[j];
        }
        for (int i = 0; i < 4; ++i)
            for (int j = 0; j < 2; ++j) {
                accg[i][j] = mfma16(af[i], bg[j], accg[i][j]);
                accu[i][j] = mfma16(af[i], bu[j], accu[i][j]);
            }
    }

    const float s_g = *sgp;
    const float s_u = *sup;
    // C/D layout: col = lane&15 (N), row = quad*4 + reg (M)
    for (int i = 0; i < 4; ++i) {
        const size_t row = m0 + wr * 64 + i * 16 + quad * 4;
        for (int j = 0; j < 2; ++j) {
            const size_t col = n0 + wc * 32 + j * 16 + l16;
            for (int r = 0; r < 4; ++r) {
                float g = accg[i][j][r] * s_g;
                float u = accu[i][j][r] * s_u;
                float sig = 1.0f / (1.0f + __expf(-g));
                float v = g * sig * u;
                mid[(row + r) * HIDDEN + col] = f2bf(v);
            }
        }
    }
}

// ---------------- GEMM2: down projection ----------------
// A = mid [MTOK,HIDDEN] bf16; B = w_down [DIM,HIDDEN] bf16 (NT).
// 128x128 block tile, 4 waves of 64x64, fp32 output with scale.
__global__ __launch_bounds__(256) void gemm_down(
    const unsigned short* __restrict__ A,
    const unsigned short* __restrict__ B,
    float* __restrict__ out,
    const float* __restrict__ sdp)
{
    __shared__ __align__(16) unsigned short sA[128 * 32];
    __shared__ __align__(16) unsigned short sB[128 * 32];

    const int tid  = threadIdx.x;
    const int lane = tid & 63;
    const int wave = tid >> 6;
    const int wr   = wave >> 1;
    const int wc   = wave & 1;
    const int quad = lane >> 4;
    const int l16  = lane & 15;

    const size_t m0 = (size_t)blockIdx.x * 128;
    const size_t n0 = (size_t)blockIdx.y * 128;

    const int srow = tid >> 2;
    const int scol = (tid & 3) * 8;

    const unsigned short* gA0 = A + (m0 + srow) * HIDDEN + scol;
    const unsigned short* gA1 = gA0 + (size_t)64 * HIDDEN;
    const unsigned short* gB0 = B + (n0 + srow) * HIDDEN + scol;
    const unsigned short* gB1 = gB0 + (size_t)64 * HIDDEN;

    unsigned short* lA0 = &sA[tid * 8];
    unsigned short* lA1 = &sA[(tid + 256) * 8];
    unsigned short* lB0 = &sB[tid * 8];
    unsigned short* lB1 = &sB[(tid + 256) * 8];

    const unsigned short* rA[4];
    const unsigned short* rB[4];
    for (int i = 0; i < 4; ++i) {
        rA[i] = &sA[(wr * 64 + i * 16 + l16) * 32 + quad * 8];
        rB[i] = &sB[(wc * 64 + i * 16 + l16) * 32 + quad * 8];
    }

    floatx4 acc[4][4];
    const floatx4 zero = {0.f, 0.f, 0.f, 0.f};
    for (int i = 0; i < 4; ++i)
        for (int j = 0; j < 4; ++j) acc[i][j] = zero;

    for (int kt = 0; kt < HIDDEN / 32; ++kt) {
        __syncthreads();
        gload16(gA0, lA0);
        gload16(gA1, lA1);
        gload16(gB0, lB0);
        gload16(gB1, lB1);
        gA0 += 32; gA1 += 32; gB0 += 32; gB1 += 32;
        __syncthreads();

        bf16x8 af[4], bf[4];
        for (int i = 0; i < 4; ++i) {
            af[i] = *(const bf16x8*)rA[i];
            bf[i] = *(const bf16x8*)rB[i];
        }
        for (int i = 0; i < 4; ++i)
            for (int j = 0; j < 4; ++j)
                acc[i][j] = mfma16(af[i], bf[j], acc[i][j]);
    }

    const float s_d = *sdp;
    for (int i = 0; i < 4; ++i) {
        const size_t row = m0 + wr * 64 + i * 16 + quad * 4;
        for (int j = 0; j < 4; ++j) {
            const size_t col = n0 + wc * 64 + j * 16 + l16;
            for (int r = 0; r < 4; ++r)
                out[(row + r) * DIM + col] = acc[i][j][r] * s_d;
        }
    }
}

// ---------------- launch ----------------

extern "C" void kernel_launch(void* const* d_in, const int* in_sizes, int n_in,
                              void* d_out, int out_size, void* d_ws, size_t ws_size,
                              hipStream_t stream) {
    const float* x  = (const float*)d_in[0];
    const int*   wg = (const int*)d_in[1];
    const int*   wu = (const int*)d_in[2];
    const int*   wd = (const int*)d_in[3];
    const float* sg = (const float*)d_in[4];
    const float* su = (const float*)d_in[5];
    const float* sd = (const float*)d_in[6];
    float* out = (float*)d_out;

    // workspace carve-up (all bf16 as ushort). Total = 517,996,544 bytes.
    unsigned short* xb   = (unsigned short*)d_ws;
    unsigned short* wgb  = xb  + (size_t)MTOK * DIM;      //  67.1 MB in
    unsigned short* wub  = wgb + (size_t)HIDDEN * DIM;    //  90.2 MB
    unsigned short* wdb  = wub + (size_t)HIDDEN * DIM;    //  90.2 MB
    unsigned short* midb = wdb + (size_t)DIM * HIDDEN;    //  90.2 MB; mid = 180.4 MB

    // 1) dtype conversions (weights are ints in [-127,127] -> exact in bf16)
    {
        int n4 = MTOK * DIM / 4;
        cvt_f32_bf16<<<dim3((n4 + 255) / 256), 256, 0, stream>>>((const float4*)x, (ushort4*)xb, n4);
    }
    {
        int n4 = HIDDEN * DIM / 4;
        cvt_i32_bf16<<<dim3((n4 + 255) / 256), 256, 0, stream>>>((const int4*)wg, (ushort4*)wgb, n4);
        cvt_i32_bf16<<<dim3((n4 + 255) / 256), 256, 0, stream>>>((const int4*)wu, (ushort4*)wub, n4);
        cvt_i32_bf16<<<dim3((n4 + 255) / 256), 256, 0, stream>>>((const int4*)wd, (ushort4*)wdb, n4);
    }

    // 2) fused gate+up GEMM + SwiGLU -> mid (bf16)
    gemm_gateup<<<dim3(MTOK / 128, HIDDEN / 64), 256, 0, stream>>>(xb, wgb, wub, midb, sg, su);

    // 3) down GEMM -> out (fp32)
    gemm_down<<<dim3(MTOK / 128, DIM / 128), 256, 0, stream>>>(midb, wdb, out, sd);
}